// Round 10
// baseline (338.835 us; speedup 1.0000x reference)
//
#include <hip/hip_runtime.h>
#include <algorithm>

// CausalSelfAttention  B=2, T=2048, C=768, H=12, hs=64 — round 10.
// Reverts to the round-7 kernel set (best measured: 162.9us); rounds 8/9
// regressed. Single change: attn K-SPLIT. Evidence: attn pinned at 42-45us
// across 3 schedulers + 2 mfma shapes -> serial-chain bound (longest item =
// 32 k-tiles, online-softmax dependency). Items qt>=16 split into two
// k-range halves ([0,H),[H,qt+1)); partials (m,l,O) go to ws scratch (one
// slot per half); second finisher (atomic flag + threadfence release/acquire)
// merges and stores. Chains <=16.5 tiles; 1152 items >= 1024-block queue.
// Flags zeroed per replay in fused_prep. Inner attn body = round-7 verbatim.

#define BB 2
#define TT 2048
#define CC 768
#define C3 2304
#define HH 12
#define DD 64
#define MM 4096   // B*T
#define NITEMS 1152
#define NPAIRS 384
#define SLOTF (64 * 66)   // floats per half-slot: m[64], l[64], O[64][64]

typedef unsigned short u16;
typedef unsigned int u32;
typedef __attribute__((ext_vector_type(8))) u16 u16x8;
typedef __attribute__((ext_vector_type(8))) __bf16 bf16x8;
typedef __attribute__((ext_vector_type(4))) float f32x4;

__device__ __forceinline__ float u2f(u16 u) {
    union { u32 i; float f; } c; c.i = ((u32)u) << 16; return c.f;
}
__device__ __forceinline__ u16 f2u(float f) {
    union { float f; u32 i; } c; c.f = f;
    u32 x = c.i;
    return (u16)((x + 0x7FFFu + ((x >> 16) & 1u)) >> 16);  // RNE
}
__device__ __forceinline__ u16 f2b(float f) {              // RNE via v_cvt
    __bf16 h = (__bf16)f; return __builtin_bit_cast(u16, h);
}
__device__ __forceinline__ bf16x8 ldsb8(const u16* p) {
    return __builtin_bit_cast(bf16x8, *(const u16x8*)p);
}
__device__ __forceinline__ f32x4 mfma16(bf16x8 a, bf16x8 b, f32x4 c) {
    return __builtin_amdgcn_mfma_f32_16x16x32_bf16(a, b, c, 0, 0, 0);
}
typedef __attribute__((address_space(1))) const u32 gu32;
typedef __attribute__((address_space(3))) u32 lu32;
__device__ __forceinline__ void gload16(const u16* gp, u16* lp) {
    __builtin_amdgcn_global_load_lds((gu32*)(const void*)gp, (lu32*)(void*)lp,
                                     16, 0, 0);
}
__device__ __forceinline__ void barrier_raw() {
    asm volatile("" ::: "memory");
    __builtin_amdgcn_s_barrier();
    asm volatile("" ::: "memory");
}

// ---------------------------------------------------------------------------
// Fast detector (round-5 verified).
// ---------------------------------------------------------------------------
__global__ void detect_kernel(const u16* __restrict__ x, int* __restrict__ flag)
{
    __shared__ int found;
    if (threadIdx.x == 0) found = 0;
    __syncthreads();
    int local = 0;
    const u16x8* p = (const u16x8*)x + threadIdx.x;
    #pragma unroll
    for (int i = 0; i < 8; ++i) {
        const u16x8 v = p[(size_t)i * 256];
        #pragma unroll
        for (int j = 0; j < 8; ++j)
            if ((v[j] & 0x7F80u) == 0x7F80u) local = 1;
    }
    if (local) atomicOr(&found, 1);
    __syncthreads();
    if (threadIdx.x == 0) *flag = found ? 1 : 0;
}

// ---------------------------------------------------------------------------
// Fused prep (round-7 verified) + per-replay zeroing of qcnt/pairflag.
// ---------------------------------------------------------------------------
__device__ void prep_w_body(const void* __restrict__ Wv, u16* __restrict__ Wt,
                            int K, int N, int bx, int by, int fm,
                            u16 (*Ts)[72])
{
    const int t = threadIdx.x;
    const int n0 = bx * 64, k0 = by * 64;
    const int r = t >> 2, c0 = (t & 3) << 4;

    if (fm) {
        const float* W = (const float*)Wv + (size_t)(k0 + r) * N + n0 + c0;
        #pragma unroll
        for (int i = 0; i < 16; i += 4) {
            const float4 v = *(const float4*)(W + i);
            Ts[c0 + i + 0][r] = f2u(v.x);
            Ts[c0 + i + 1][r] = f2u(v.y);
            Ts[c0 + i + 2][r] = f2u(v.z);
            Ts[c0 + i + 3][r] = f2u(v.w);
        }
    } else {
        const u16* W = (const u16*)Wv + (size_t)(k0 + r) * N + n0 + c0;
        const u16x8 a = *(const u16x8*)W;
        const u16x8 c = *(const u16x8*)(W + 8);
        #pragma unroll
        for (int i = 0; i < 8; ++i) { Ts[c0 + i][r] = a[i]; Ts[c0 + 8 + i][r] = c[i]; }
    }
    __syncthreads();
    u16* o = Wt + (size_t)(n0 + r) * K + k0 + c0;
    *(u16x8*)o = *(const u16x8*)&Ts[r][c0];
    *(u16x8*)(o + 8) = *(const u16x8*)&Ts[r][c0 + 8];
}

__global__ __launch_bounds__(256)
void fused_prep(const void* __restrict__ x, const void* __restrict__ Wa,
                const void* __restrict__ ba, const void* __restrict__ Wp,
                const void* __restrict__ bp,
                u16* __restrict__ xb, u16* __restrict__ WaT,
                u16* __restrict__ WpT, u16* __restrict__ bao,
                u16* __restrict__ bpo,
                const int* __restrict__ flag, int mode,
                int* __restrict__ qcnt, int* __restrict__ pairflag)
{
    __shared__ u16 Ts[64][72];
    const int fm = (mode >= 0) ? mode : *flag;
    const int blk = blockIdx.x;
    const int t = threadIdx.x;

    if (blk < 432) {                       // W_attn: grid 36 x 12
        prep_w_body(Wa, WaT, CC, C3, blk % 36, blk / 36, fm, Ts);
    } else if (blk < 576) {                // W_proj: grid 12 x 12
        const int b2 = blk - 432;
        prep_w_body(Wp, WpT, CC, CC, b2 % 12, b2 / 12, fm, Ts);
    } else if (blk < 2112) {               // x -> bf16 (octets), fp32 mode only
        if (fm == 0) return;
        const size_t i = (size_t)(blk - 576) * 256 + t;
        const float* xp = (const float*)x + i * 8;
        u16x8 o;
        #pragma unroll
        for (int j = 0; j < 8; ++j) o[j] = f2u(xp[j]);
        *(u16x8*)(xb + i * 8) = o;
    } else {                               // biases + attn bookkeeping reset
        const int i = (blk - 2112) * 256 + t;
        if (blk == 2112 && t == 0) *qcnt = 0;
        if (i < NPAIRS) pairflag[i] = 0;
        if (i < C3) bao[i] = fm ? f2u(((const float*)ba)[i]) : ((const u16*)ba)[i];
        if (i < CC) bpo[i] = fm ? f2u(((const float*)bp)[i]) : ((const u16*)bp)[i];
    }
}

// ---------------------------------------------------------------------------
// MFMA GEMM (round-7 verified, unchanged).
// ---------------------------------------------------------------------------
template <int FRM, int FRN>
__global__ __launch_bounds__(256)
void gemm_mfma(const u16* __restrict__ Adir, const u16* __restrict__ Acnv,
               const u16* __restrict__ Bt, const u16* __restrict__ bias,
               void* __restrict__ outv, int M, int N, int K,
               const int* __restrict__ flag, int mode, int om_sel)
{
    constexpr int TSM = 32 * FRM, TSN = 32 * FRN;
    constexpr int LPA = TSM / 64;
    constexpr int LPB = TSN / 64;

    __shared__ u16 As[2][TSM * 32];
    __shared__ u16 Bs[2][TSN * 32];

    const int fm = (mode >= 0) ? mode : *flag;
    const u16* A = fm ? Acnv : Adir;
    const int om = om_sel ? fm : 0;

    const int nwg = gridDim.x;
    const int lin = (blockIdx.x & 7) * (nwg >> 3) + (blockIdx.x >> 3);
    const int nx = N / TSN;
    const int m0 = (lin / nx) * TSM, n0 = (lin % nx) * TSN;

    const int t = threadIdx.x;
    const int lane = t & 63, wave = t >> 6;
    const int wm = wave >> 1, wn = wave & 1;
    const int l15 = lane & 15, h4 = lane >> 4;

    const int rsub = lane >> 2;
    const int cs = ((lane & 3) ^ ((lane >> 4) & 3)) * 8;
    const u16* Ab[LPA];
    const u16* Bb[LPB];
    #pragma unroll
    for (int j = 0; j < LPA; ++j)
        Ab[j] = A + (size_t)(m0 + wave * (16 * LPA) + j * 16 + rsub) * K + cs;
    #pragma unroll
    for (int j = 0; j < LPB; ++j)
        Bb[j] = Bt + (size_t)(n0 + wave * (16 * LPB) + j * 16 + rsub) * K + cs;

    f32x4 acc[FRM][FRN];
    #pragma unroll
    for (int i = 0; i < FRM; ++i)
        #pragma unroll
        for (int j = 0; j < FRN; ++j) acc[i][j] = (f32x4){0.f, 0.f, 0.f, 0.f};

    const int csr = (h4 ^ (l15 >> 2)) * 8;
    const int arow = wm * (TSM / 2) + l15;
    const int brow = wn * (TSN / 2) + l15;

    const int NT = K >> 5;
    #pragma unroll
    for (int j = 0; j < LPA; ++j)
        gload16(Ab[j], &As[0][(wave * LPA + j) * 512]);
    #pragma unroll
    for (int j = 0; j < LPB; ++j)
        gload16(Bb[j], &Bs[0][(wave * LPB + j) * 512]);

    for (int kt = 0; kt < NT; ++kt) {
        const int cur = kt & 1;
        if (kt + 1 < NT) {
            const int k0 = (kt + 1) << 5;
            const int nb = cur ^ 1;
            #pragma unroll
            for (int j = 0; j < LPA; ++j)
                gload16(Ab[j] + k0, &As[nb][(wave * LPA + j) * 512]);
            #pragma unroll
            for (int j = 0; j < LPB; ++j)
                gload16(Bb[j] + k0, &Bs[nb][(wave * LPB + j) * 512]);
            if constexpr (LPA + LPB == 4)
                asm volatile("s_waitcnt vmcnt(4)" ::: "memory");
            else if constexpr (LPA + LPB == 3)
                asm volatile("s_waitcnt vmcnt(3)" ::: "memory");
            else
                asm volatile("s_waitcnt vmcnt(2)" ::: "memory");
        } else {
            asm volatile("s_waitcnt vmcnt(0)" ::: "memory");
        }
        barrier_raw();

        bf16x8 af[FRM], bfr[FRN];
        #pragma unroll
        for (int f = 0; f < FRM; ++f)
            af[f] = ldsb8(&As[cur][(arow + f * 16) * 32 + csr]);
        #pragma unroll
        for (int f = 0; f < FRN; ++f)
            bfr[f] = ldsb8(&Bs[cur][(brow + f * 16) * 32 + csr]);
        #pragma unroll
        for (int i = 0; i < FRM; ++i)
            #pragma unroll
            for (int j = 0; j < FRN; ++j)
                acc[i][j] = mfma16(af[i], bfr[j], acc[i][j]);

        barrier_raw();
    }

    const int orow = m0 + wm * (TSM / 2) + h4 * 4;
    const int ocol = n0 + wn * (TSN / 2) + l15;
    if (om == 0) {
        u16* out = (u16*)outv;
        #pragma unroll
        for (int i = 0; i < FRM; ++i)
            #pragma unroll
            for (int j = 0; j < FRN; ++j) {
                const int col = ocol + j * 16;
                const float bv = u2f(bias[col]);
                #pragma unroll
                for (int r2 = 0; r2 < 4; ++r2)
                    out[(size_t)(orow + i * 16 + r2) * N + col] = f2b(acc[i][j][r2] + bv);
            }
    } else {
        float* out = (float*)outv;
        #pragma unroll
        for (int i = 0; i < FRM; ++i)
            #pragma unroll
            for (int j = 0; j < FRN; ++j) {
                const int col = ocol + j * 16;
                const float bv = u2f(bias[col]);
                #pragma unroll
                for (int r2 = 0; r2 < 4; ++r2)
                    out[(size_t)(orow + i * 16 + r2) * N + col] = acc[i][j][r2] + bv;
            }
    }
}

// ---------------------------------------------------------------------------
// MFMA flash attention: round-7 inner body (16x16, swapped-S, rho-permuted K,
// defer-max, per-lane partial l), driven by a 1024-block queue over 1152
// K-split items. kind: 0=full [0,qt+1), 1=first [0,H), 2=second [H,qt+1).
// Split halves write (m,l,O) partials to pscr; second finisher merges.
// ---------------------------------------------------------------------------
__global__ __launch_bounds__(256)
void attn_mfma(const u16* __restrict__ qkv, u16* __restrict__ yatt,
               const int* __restrict__ tab, int* __restrict__ qcnt,
               int* __restrict__ pairflag, float* __restrict__ pscr)
{
    __shared__ u16 Ks[2][64][72];   // [buf][rho(k)][d]
    __shared__ u16 Vt[2][64][72];   // [buf][d][k]
    __shared__ int s_idx, s_old;

    const int t = threadIdx.x;
    const int lane = t & 63, w = t >> 6;
    const int l15 = lane & 15, h4 = lane >> 4;

    const int sr = t >> 2;
    const int sd = (t & 3) << 4;
    const int rho = ((sr >> 5) & 1) * 32 + ((sr >> 2) & 1) * 16 +
                    ((sr >> 3) & 3) * 4 + (sr & 3);
    const int vk = (t & 31) * 2;
    const int vd = (t >> 5) << 3;

    for (;;) {
        if (t == 0) s_idx = atomicAdd(qcnt, 1);
        __syncthreads();
        const int idx = s_idx;
        if (idx >= NITEMS) return;
        const int code = tab[idx];
        const int qt = code & 255, hb = (code >> 8) & 255, kind = code >> 16;
        const int h = hb % HH, b = hb / HH;
        const int q0 = qt * 64;
        const int H = (qt + 1) >> 1;
        const int kt0 = (kind == 2) ? H : 0;
        const int ktE = (kind == 1) ? H : qt + 1;
        const int NT = ktE - kt0;

        // ---- Q in registers, pre-scaled by 1/8 (exact pow2) ----
        bf16x8 aq0, aq1;
        {
            const u16* qp = qkv + ((size_t)(b * TT + q0 + w * 16 + l15)) * C3
                            + h * DD + h4 * 8;
            const u16x8 v0 = *(const u16x8*)qp;
            const u16x8 v1 = *(const u16x8*)(qp + 32);
            #pragma unroll
            for (int i = 0; i < 8; ++i) {
                aq0[i] = (__bf16)(u2f(v0[i]) * 0.125f);
                aq1[i] = (__bf16)(u2f(v1[i]) * 0.125f);
            }
        }

        float m_i = -1e30f, l_p = 0.f;
        f32x4 O[4];
        #pragma unroll
        for (int d = 0; d < 4; ++d) O[d] = (f32x4){0.f, 0.f, 0.f, 0.f};

        const u16* kB = qkv + ((size_t)(b * TT + sr)) * C3 + CC + h * DD + sd
                        + (size_t)kt0 * 64 * C3;
        const u16* vB = qkv + ((size_t)(b * TT + vk)) * C3 + 2 * CC + h * DD + vd
                        + (size_t)kt0 * 64 * C3;

        // ---- prologue: load+stage tile kt0, prefetch kt0+1 ----
        u16x8 kr0 = *(const u16x8*)kB;
        u16x8 kr1 = *(const u16x8*)(kB + 8);
        u16x8 vr0 = *(const u16x8*)vB;
        u16x8 vr1 = *(const u16x8*)(vB + C3);
        *(u16x8*)&Ks[0][rho][sd]     = kr0;
        *(u16x8*)&Ks[0][rho][sd + 8] = kr1;
        #pragma unroll
        for (int i = 0; i < 8; ++i)
            *(u32*)&Vt[0][vd + i][vk] = (u32)vr0[i] | ((u32)vr1[i] << 16);
        if (NT > 1) {
            const u16* kp = kB + (size_t)64 * C3;
            const u16* vp = vB + (size_t)64 * C3;
            kr0 = *(const u16x8*)kp;
            kr1 = *(const u16x8*)(kp + 8);
            vr0 = *(const u16x8*)vp;
            vr1 = *(const u16x8*)(vp + C3);
        }
        __syncthreads();

        const int qg = q0 + w * 16 + l15;      // this lane's q row (global)

        for (int kk = 0; kk < NT; ++kk) {
            const int cur = kk & 1;

            // ---- S = K Q^T (swapped; scale folded into Q) ----
            f32x4 s[4];
            __builtin_amdgcn_s_setprio(1);
            #pragma unroll
            for (int kf = 0; kf < 4; ++kf) {
                f32x4 z = (f32x4){0.f, 0.f, 0.f, 0.f};
                z = mfma16(ldsb8(&Ks[cur][kf * 16 + l15][h4 * 8]), aq0, z);
                z = mfma16(ldsb8(&Ks[cur][kf * 16 + l15][32 + h4 * 8]), aq1, z);
                s[kf] = z;
            }
            __builtin_amdgcn_s_setprio(0);

            // ---- stage tile kk+1; prefetch kk+2 ----
            if (kk + 1 < NT) {
                const int nb = cur ^ 1;
                *(u16x8*)&Ks[nb][rho][sd]     = kr0;
                *(u16x8*)&Ks[nb][rho][sd + 8] = kr1;
                #pragma unroll
                for (int i = 0; i < 8; ++i)
                    *(u32*)&Vt[nb][vd + i][vk] = (u32)vr0[i] | ((u32)vr1[i] << 16);
                if (kk + 2 < NT) {
                    const u16* kp = kB + (size_t)(kk + 2) * 64 * C3;
                    const u16* vp = vB + (size_t)(kk + 2) * 64 * C3;
                    kr0 = *(const u16x8*)kp;
                    kr1 = *(const u16x8*)(kp + 8);
                    vr0 = *(const u16x8*)vp;
                    vr1 = *(const u16x8*)(vp + C3);
                }
            }

            // ---- causal mask (diagonal tile only) ----
            if (kt0 + kk == qt) {
                #pragma unroll
                for (int kf = 0; kf < 4; ++kf) {
                    const int kbase = qt * 64 + 8 * h4 + 32 * (kf >> 1) + 4 * (kf & 1);
                    #pragma unroll
                    for (int r2 = 0; r2 < 4; ++r2)
                        if (kbase + r2 > qg) s[kf][r2] = -1e30f;
                }
            }

            // ---- softmax, defer-max: no cross-lane ops in common path ----
            float pm = s[0][0];
            #pragma unroll
            for (int kf = 0; kf < 4; ++kf)
                #pragma unroll
                for (int r2 = 0; r2 < 4; ++r2) pm = fmaxf(pm, s[kf][r2]);

            if (!__all(pm <= m_i + 8.f)) {
                float pr = pm;
                pr = fmaxf(pr, __shfl_xor(pr, 16));
                pr = fmaxf(pr, __shfl_xor(pr, 32));
                const float mnew = fmaxf(m_i, pr);
                const float a_ = __expf(m_i - mnew);
                l_p *= a_;
                float alf[4];
                #pragma unroll
                for (int r2 = 0; r2 < 4; ++r2) alf[r2] = __shfl(a_, h4 * 4 + r2);
                #pragma unroll
                for (int d = 0; d < 4; ++d)
                    #pragma unroll
                    for (int r2 = 0; r2 < 4; ++r2) O[d][r2] *= alf[r2];
                m_i = mnew;
            }

            bf16x8 ap, ap2;
            float rs = 0.f;
            #pragma unroll
            for (int kf = 0; kf < 2; ++kf)
                #pragma unroll
                for (int r2 = 0; r2 < 4; ++r2) {
                    const float p = __expf(s[kf][r2] - m_i);
                    rs += p;
                    ap[kf * 4 + r2] = (__bf16)p;
                }
            #pragma unroll
            for (int kf = 2; kf < 4; ++kf)
                #pragma unroll
                for (int r2 = 0; r2 < 4; ++r2) {
                    const float p = __expf(s[kf][r2] - m_i);
                    rs += p;
                    ap2[(kf - 2) * 4 + r2] = (__bf16)p;
                }
            l_p += rs;

            // ---- O += P V (P entirely in registers) ----
            __builtin_amdgcn_s_setprio(1);
            #pragma unroll
            for (int d = 0; d < 4; ++d) {
                O[d] = mfma16(ap,  ldsb8(&Vt[cur][d * 16 + l15][h4 * 8]), O[d]);
                O[d] = mfma16(ap2, ldsb8(&Vt[cur][d * 16 + l15][32 + h4 * 8]), O[d]);
            }
            __builtin_amdgcn_s_setprio(0);

            __syncthreads();               // one barrier per tile
        }

        // ---- epilogue ----
        float lr = l_p;
        lr += __shfl_xor(lr, 16);
        lr += __shfl_xor(lr, 32);

        if (kind == 0) {                   // full item: direct store (R7 path)
            const float invl = 1.0f / lr;
            float inv[4];
            #pragma unroll
            for (int r2 = 0; r2 < 4; ++r2) inv[r2] = __shfl(invl, h4 * 4 + r2);
            u16* yp = yatt + ((size_t)(b * TT + q0 + w * 16 + h4 * 4)) * CC
                      + h * DD + l15;
            #pragma unroll
            for (int r2 = 0; r2 < 4; ++r2)
                #pragma unroll
                for (int d = 0; d < 4; ++d)
                    yp[(size_t)r2 * CC + d * 16] = f2b(O[d][r2] * inv[r2]);
        } else {                           // half item: partial + maybe merge
            const int p = (qt - 16) * (HH * BB) + hb;
            float* slot = pscr + ((size_t)p * 2 + (kind - 1)) * SLOTF;
            const int rq = w * 16 + l15;
            slot[rq] = m_i;                // row-uniform (4x redundant, benign)
            slot[64 + rq] = lr;
            #pragma unroll
            for (int r2 = 0; r2 < 4; ++r2)
                #pragma unroll
                for (int d = 0; d < 4; ++d)
                    slot[128 + (size_t)(w * 16 + h4 * 4 + r2) * 64 + l15 + d * 16]
                        = O[d][r2];
            __threadfence();               // release: partial visible pre-flag
            __syncthreads();
            if (t == 0) s_old = atomicAdd(&pairflag[p], 1);
            __syncthreads();
            if (s_old == 1) {              // second finisher: merge + store
                __threadfence();           // acquire: partner's writes visible
                const float* oth = pscr + ((size_t)p * 2 + (2 - kind)) * SLOTF;
                u16* yp = yatt + ((size_t)(b * TT + q0 + w * 16 + h4 * 4)) * CC
                          + h * DD + l15;
                #pragma unroll
                for (int r2 = 0; r2 < 4; ++r2) {
                    const int rr2 = w * 16 + h4 * 4 + r2;
                    const float mA = __shfl(m_i, h4 * 4 + r2);
                    const float lA = __shfl(lr, h4 * 4 + r2);
                    const float mB = oth[rr2];
                    const float lB = oth[64 + rr2];
                    const float mm = fmaxf(mA, mB);
                    const float aA = __expf(mA - mm);
                    const float aB = __expf(mB - mm);
                    const float inv = 1.0f / (lA * aA + lB * aB);
                    #pragma unroll
                    for (int d = 0; d < 4; ++d)
                        yp[(size_t)r2 * CC + d * 16] = f2b(
                            (O[d][r2] * aA +
                             oth[128 + (size_t)rr2 * 64 + l15 + d * 16] * aB) * inv);
                }
            }
        }
        __syncthreads();                   // safe to reuse LDS / s_idx
    }
}

// ---------------------------------------------------------------------------
extern "C" void kernel_launch(void* const* d_in, const int* in_sizes, int n_in,
                              void* d_out, int out_size, void* d_ws, size_t ws_size,
                              hipStream_t stream)
{
    (void)n_in; (void)out_size; (void)ws_size;

    const void* x      = d_in[0];
    const void* W_attn = d_in[1];
    const void* b_attn = d_in[2];
    const void* W_proj = d_in[3];
    const void* b_proj = d_in[4];

    // workspace layout (~43 MB; ws is >=268 MB per fill-poison size)
    u16* qkv  = (u16*)d_ws;                       // [4096,2304] bf16
    u16* yatt = qkv + (size_t)MM * C3;            // [4096,768]  bf16
    u16* xb   = yatt;                             // bf16 x — lifetime disjoint
    u16* WaT  = yatt + (size_t)MM * CC;           // [2304,768]  bf16 (W_attn^T)
    u16* WpT  = WaT + (size_t)C3 * CC;            // [768,768]   bf16 (W_proj^T)
    u16* ba   = WpT + (size_t)CC * CC;            // [2304] bf16
    u16* bp   = ba + C3;                          // [768]  bf16
    int* flag = (int*)(bp + CC);                  // 1 int
    int* qcnt = flag + 1;                         // queue counter
    int* dtab = qcnt + 1;                         // 1152 ints (LPT item table)
    int* pairflag = dtab + NITEMS;                // 384 ints
    float* pscr = (float*)(pairflag + NPAIRS);    // 2*384 half-slots (13 MB)

    // host-built LPT item table (longest chains first), copied once per launch
    static int host_tab[NITEMS];
    static bool tab_init = false;
    if (!tab_init) {
        struct It { int len, code; };
        It tmp[NITEMS];
        int n = 0;
        for (int qt = 0; qt < 32; ++qt)
            for (int hb = 0; hb < HH * BB; ++hb) {
                if (qt < 16) {
                    tmp[n++] = {qt + 1, qt | (hb << 8) | (0 << 16)};
                } else {
                    const int H = (qt + 1) >> 1;
                    tmp[n++] = {H, qt | (hb << 8) | (1 << 16)};
                    tmp[n++] = {qt + 1 - H, qt | (hb << 8) | (2 << 16)};
                }
            }
        std::sort(tmp, tmp + n,
                  [](const It& a, const It& b) { return a.len > b.len; });
        for (int i = 0; i < n; ++i) host_tab[i] = tmp[i].code;
        tab_init = true;
    }
    hipMemcpyAsync(dtab, host_tab, sizeof(host_tab), hipMemcpyHostToDevice,
                   stream);

    // host-side dtype inference; device detector as fallback
    int mode = -1;
    if (in_sizes[0] == MM * CC * 4) mode = 1;          // fp32 bytes
    else if (in_sizes[0] == MM * CC * 2) mode = 0;     // bf16 bytes
    if (mode < 0) {
        detect_kernel<<<1, 256, 0, stream>>>((const u16*)x, flag);
    }

    // fused prep: W transposes + x->bf16 + biases + counter/flag reset
    fused_prep<<<2121, 256, 0, stream>>>(x, W_attn, b_attn, W_proj, b_proj,
                                         xb, WaT, WpT, ba, bp, flag, mode,
                                         qcnt, pairflag);

    // 1) qkv = x/xb @ W_attn + b_attn (bf16 out), 128x64 tiles, 1152 blocks
    gemm_mfma<4, 2><<<(MM / 128) * (C3 / 64), 256, 0, stream>>>(
        (const u16*)x, xb, WaT, ba, (void*)qkv, MM, C3, CC, flag, mode, 0);

    // 2) causal flash attention (1024-block queue over 1152 K-split items)
    attn_mfma<<<dim3(1024, 1, 1), 256, 0, stream>>>(qkv, yatt, dtab, qcnt,
                                                    pairflag, pscr);

    // 3) out = yatt @ W_proj + b_proj (out dtype follows mode), 64x64 tiles
    gemm_mfma<2, 2><<<(MM / 64) * (CC / 64), 256, 0, stream>>>(
        yatt, yatt, WpT, bp, d_out, MM, CC, CC, flag, mode, 1);
}

// Round 11
// 190.457 us; speedup vs baseline: 1.7791x; 1.7791x over previous
//
#include <hip/hip_runtime.h>

// CausalSelfAttention  B=2, T=2048, C=768, H=12, hs=64 — round 11.
// Full revert to round-7 set (162.9us, twice-verified); round 10's global
// K-split regressed 2x (device-scope fences -> L2 writebacks).
// Single change: attn K staging removed — cycle model shows the LDS pipe is
// the saturated resource (262 cyc/wave/tile; x4 waves x3 blocks ~= measured
// 3360 cyc/tile). K fragments now load DIRECT from global (L2-hot; row map
// g = (kf>>1)*32+(kf&1)*4+((l15>>3)&1)*16+((l15>>2)&1)*8+(l15&3), the closed
// form of the verified rho-permutation -> identical fragment algebra).
// LDS/tile -46%; LDS size 36.9 -> 18.4 KB. V path/softmax/epilogue verbatim.

#define BB 2
#define TT 2048
#define CC 768
#define C3 2304
#define HH 12
#define DD 64
#define MM 4096   // B*T

typedef unsigned short u16;
typedef unsigned int u32;
typedef __attribute__((ext_vector_type(8))) u16 u16x8;
typedef __attribute__((ext_vector_type(8))) __bf16 bf16x8;
typedef __attribute__((ext_vector_type(4))) float f32x4;

__device__ __forceinline__ float u2f(u16 u) {
    union { u32 i; float f; } c; c.i = ((u32)u) << 16; return c.f;
}
__device__ __forceinline__ u16 f2u(float f) {
    union { float f; u32 i; } c; c.f = f;
    u32 x = c.i;
    return (u16)((x + 0x7FFFu + ((x >> 16) & 1u)) >> 16);  // RNE
}
__device__ __forceinline__ u16 f2b(float f) {              // RNE via v_cvt
    __bf16 h = (__bf16)f; return __builtin_bit_cast(u16, h);
}
__device__ __forceinline__ bf16x8 ldsb8(const u16* p) {
    return __builtin_bit_cast(bf16x8, *(const u16x8*)p);
}
__device__ __forceinline__ bf16x8 asbf(u16x8 v) {
    return __builtin_bit_cast(bf16x8, v);
}
__device__ __forceinline__ f32x4 mfma16(bf16x8 a, bf16x8 b, f32x4 c) {
    return __builtin_amdgcn_mfma_f32_16x16x32_bf16(a, b, c, 0, 0, 0);
}
typedef __attribute__((address_space(1))) const u32 gu32;
typedef __attribute__((address_space(3))) u32 lu32;
__device__ __forceinline__ void gload16(const u16* gp, u16* lp) {
    __builtin_amdgcn_global_load_lds((gu32*)(const void*)gp, (lu32*)(void*)lp,
                                     16, 0, 0);
}
__device__ __forceinline__ void barrier_raw() {
    asm volatile("" ::: "memory");
    __builtin_amdgcn_s_barrier();
    asm volatile("" ::: "memory");
}

// ---------------------------------------------------------------------------
// Fast detector (round-5 verified).
// ---------------------------------------------------------------------------
__global__ void detect_kernel(const u16* __restrict__ x, int* __restrict__ flag)
{
    __shared__ int found;
    if (threadIdx.x == 0) found = 0;
    __syncthreads();
    int local = 0;
    const u16x8* p = (const u16x8*)x + threadIdx.x;
    #pragma unroll
    for (int i = 0; i < 8; ++i) {
        const u16x8 v = p[(size_t)i * 256];
        #pragma unroll
        for (int j = 0; j < 8; ++j)
            if ((v[j] & 0x7F80u) == 0x7F80u) local = 1;
    }
    if (local) atomicOr(&found, 1);
    __syncthreads();
    if (threadIdx.x == 0) *flag = found ? 1 : 0;
}

// ---------------------------------------------------------------------------
// Fused prep (round-7 verified).
// ---------------------------------------------------------------------------
__device__ void prep_w_body(const void* __restrict__ Wv, u16* __restrict__ Wt,
                            int K, int N, int bx, int by, int fm,
                            u16 (*Ts)[72])
{
    const int t = threadIdx.x;
    const int n0 = bx * 64, k0 = by * 64;
    const int r = t >> 2, c0 = (t & 3) << 4;

    if (fm) {
        const float* W = (const float*)Wv + (size_t)(k0 + r) * N + n0 + c0;
        #pragma unroll
        for (int i = 0; i < 16; i += 4) {
            const float4 v = *(const float4*)(W + i);
            Ts[c0 + i + 0][r] = f2u(v.x);
            Ts[c0 + i + 1][r] = f2u(v.y);
            Ts[c0 + i + 2][r] = f2u(v.z);
            Ts[c0 + i + 3][r] = f2u(v.w);
        }
    } else {
        const u16* W = (const u16*)Wv + (size_t)(k0 + r) * N + n0 + c0;
        const u16x8 a = *(const u16x8*)W;
        const u16x8 c = *(const u16x8*)(W + 8);
        #pragma unroll
        for (int i = 0; i < 8; ++i) { Ts[c0 + i][r] = a[i]; Ts[c0 + 8 + i][r] = c[i]; }
    }
    __syncthreads();
    u16* o = Wt + (size_t)(n0 + r) * K + k0 + c0;
    *(u16x8*)o = *(const u16x8*)&Ts[r][c0];
    *(u16x8*)(o + 8) = *(const u16x8*)&Ts[r][c0 + 8];
}

__global__ __launch_bounds__(256)
void fused_prep(const void* __restrict__ x, const void* __restrict__ Wa,
                const void* __restrict__ ba, const void* __restrict__ Wp,
                const void* __restrict__ bp,
                u16* __restrict__ xb, u16* __restrict__ WaT,
                u16* __restrict__ WpT, u16* __restrict__ bao,
                u16* __restrict__ bpo,
                const int* __restrict__ flag, int mode)
{
    __shared__ u16 Ts[64][72];
    const int fm = (mode >= 0) ? mode : *flag;
    const int blk = blockIdx.x;
    const int t = threadIdx.x;

    if (blk < 432) {                       // W_attn: grid 36 x 12
        prep_w_body(Wa, WaT, CC, C3, blk % 36, blk / 36, fm, Ts);
    } else if (blk < 576) {                // W_proj: grid 12 x 12
        const int b2 = blk - 432;
        prep_w_body(Wp, WpT, CC, CC, b2 % 12, b2 / 12, fm, Ts);
    } else if (blk < 2112) {               // x -> bf16 (octets), fp32 mode only
        if (fm == 0) return;
        const size_t i = (size_t)(blk - 576) * 256 + t;
        const float* xp = (const float*)x + i * 8;
        u16x8 o;
        #pragma unroll
        for (int j = 0; j < 8; ++j) o[j] = f2u(xp[j]);
        *(u16x8*)(xb + i * 8) = o;
    } else {                               // biases
        const int i = (blk - 2112) * 256 + t;
        if (i < C3) bao[i] = fm ? f2u(((const float*)ba)[i]) : ((const u16*)ba)[i];
        if (i < CC) bpo[i] = fm ? f2u(((const float*)bp)[i]) : ((const u16*)bp)[i];
    }
}

// ---------------------------------------------------------------------------
// MFMA GEMM (round-7 verified, unchanged).
// ---------------------------------------------------------------------------
template <int FRM, int FRN>
__global__ __launch_bounds__(256)
void gemm_mfma(const u16* __restrict__ Adir, const u16* __restrict__ Acnv,
               const u16* __restrict__ Bt, const u16* __restrict__ bias,
               void* __restrict__ outv, int M, int N, int K,
               const int* __restrict__ flag, int mode, int om_sel)
{
    constexpr int TSM = 32 * FRM, TSN = 32 * FRN;
    constexpr int LPA = TSM / 64;
    constexpr int LPB = TSN / 64;

    __shared__ u16 As[2][TSM * 32];
    __shared__ u16 Bs[2][TSN * 32];

    const int fm = (mode >= 0) ? mode : *flag;
    const u16* A = fm ? Acnv : Adir;
    const int om = om_sel ? fm : 0;

    const int nwg = gridDim.x;
    const int lin = (blockIdx.x & 7) * (nwg >> 3) + (blockIdx.x >> 3);
    const int nx = N / TSN;
    const int m0 = (lin / nx) * TSM, n0 = (lin % nx) * TSN;

    const int t = threadIdx.x;
    const int lane = t & 63, wave = t >> 6;
    const int wm = wave >> 1, wn = wave & 1;
    const int l15 = lane & 15, h4 = lane >> 4;

    const int rsub = lane >> 2;
    const int cs = ((lane & 3) ^ ((lane >> 4) & 3)) * 8;
    const u16* Ab[LPA];
    const u16* Bb[LPB];
    #pragma unroll
    for (int j = 0; j < LPA; ++j)
        Ab[j] = A + (size_t)(m0 + wave * (16 * LPA) + j * 16 + rsub) * K + cs;
    #pragma unroll
    for (int j = 0; j < LPB; ++j)
        Bb[j] = Bt + (size_t)(n0 + wave * (16 * LPB) + j * 16 + rsub) * K + cs;

    f32x4 acc[FRM][FRN];
    #pragma unroll
    for (int i = 0; i < FRM; ++i)
        #pragma unroll
        for (int j = 0; j < FRN; ++j) acc[i][j] = (f32x4){0.f, 0.f, 0.f, 0.f};

    const int csr = (h4 ^ (l15 >> 2)) * 8;
    const int arow = wm * (TSM / 2) + l15;
    const int brow = wn * (TSN / 2) + l15;

    const int NT = K >> 5;
    #pragma unroll
    for (int j = 0; j < LPA; ++j)
        gload16(Ab[j], &As[0][(wave * LPA + j) * 512]);
    #pragma unroll
    for (int j = 0; j < LPB; ++j)
        gload16(Bb[j], &Bs[0][(wave * LPB + j) * 512]);

    for (int kt = 0; kt < NT; ++kt) {
        const int cur = kt & 1;
        if (kt + 1 < NT) {
            const int k0 = (kt + 1) << 5;
            const int nb = cur ^ 1;
            #pragma unroll
            for (int j = 0; j < LPA; ++j)
                gload16(Ab[j] + k0, &As[nb][(wave * LPA + j) * 512]);
            #pragma unroll
            for (int j = 0; j < LPB; ++j)
                gload16(Bb[j] + k0, &Bs[nb][(wave * LPB + j) * 512]);
            if constexpr (LPA + LPB == 4)
                asm volatile("s_waitcnt vmcnt(4)" ::: "memory");
            else if constexpr (LPA + LPB == 3)
                asm volatile("s_waitcnt vmcnt(3)" ::: "memory");
            else
                asm volatile("s_waitcnt vmcnt(2)" ::: "memory");
        } else {
            asm volatile("s_waitcnt vmcnt(0)" ::: "memory");
        }
        barrier_raw();

        bf16x8 af[FRM], bfr[FRN];
        #pragma unroll
        for (int f = 0; f < FRM; ++f)
            af[f] = ldsb8(&As[cur][(arow + f * 16) * 32 + csr]);
        #pragma unroll
        for (int f = 0; f < FRN; ++f)
            bfr[f] = ldsb8(&Bs[cur][(brow + f * 16) * 32 + csr]);
        #pragma unroll
        for (int i = 0; i < FRM; ++i)
            #pragma unroll
            for (int j = 0; j < FRN; ++j)
                acc[i][j] = mfma16(af[i], bfr[j], acc[i][j]);

        barrier_raw();
    }

    const int orow = m0 + wm * (TSM / 2) + h4 * 4;
    const int ocol = n0 + wn * (TSN / 2) + l15;
    if (om == 0) {
        u16* out = (u16*)outv;
        #pragma unroll
        for (int i = 0; i < FRM; ++i)
            #pragma unroll
            for (int j = 0; j < FRN; ++j) {
                const int col = ocol + j * 16;
                const float bv = u2f(bias[col]);
                #pragma unroll
                for (int r2 = 0; r2 < 4; ++r2)
                    out[(size_t)(orow + i * 16 + r2) * N + col] = f2b(acc[i][j][r2] + bv);
            }
    } else {
        float* out = (float*)outv;
        #pragma unroll
        for (int i = 0; i < FRM; ++i)
            #pragma unroll
            for (int j = 0; j < FRN; ++j) {
                const int col = ocol + j * 16;
                const float bv = u2f(bias[col]);
                #pragma unroll
                for (int r2 = 0; r2 < 4; ++r2)
                    out[(size_t)(orow + i * 16 + r2) * N + col] = acc[i][j][r2] + bv;
            }
    }
}

// ---------------------------------------------------------------------------
// MFMA flash attention (round-7 structure; K now DIRECT FROM GLOBAL).
// Swapped-S: s[kf] = mfma(K_frag, Q_frag); lane owns q = l15. K fragment for
// frag kf, lane (l15,h4) = global K row
//   g = (kf>>1)*32 + (kf&1)*4 + ((l15>>3)&1)*16 + ((l15>>2)&1)*8 + (l15&3)
// at d = h4*8 (lo) / 32+h4*8 (hi) — closed form of the verified rho map, so
// S registers remain exactly the PV A-fragments and the causal-mask formula
// (kbase = 8*h4 + 32*(kf>>1) + 4*(kf&1)) is unchanged. K prefetched 1 tile
// ahead into registers (L2-hot). V path: LDS ping-pong, round-7 verbatim.
// ---------------------------------------------------------------------------
__global__ __launch_bounds__(256)
void attn_mfma(const u16* __restrict__ qkv, u16* __restrict__ yatt)
{
    __shared__ u16 Vt[2][64][72];   // [buf][d][k]

    // ---- balanced work assignment (round-3 closed form) ----
    const int bid = blockIdx.x;
    const int bin = bid & 255, slot = bid >> 8;
    const int g = bin >> 5, j = bin & 31;
    int qt;
    if (slot == 0)      qt = j;
    else if (slot == 1) qt = (j + 16) & 31;
    else                qt = (j < 16) ? (30 - 2 * j) : (63 - 2 * j);
    const int hb = slot * 8 + g;
    const int h = hb % HH, b = hb / HH;

    const int t = threadIdx.x;
    const int lane = t & 63, w = t >> 6;
    const int l15 = lane & 15, h4 = lane >> 4;
    const int q0 = qt * 64;

    // V staging geometry (round-7 verified)
    const int vk = (t & 31) * 2;
    const int vd = (t >> 5) << 3;

    // ---- Q in registers, pre-scaled by 1/8 (exact pow2) ----
    bf16x8 aq0, aq1;
    {
        const u16* qp = qkv + ((size_t)(b * TT + q0 + w * 16 + l15)) * C3
                        + h * DD + h4 * 8;
        const u16x8 v0 = *(const u16x8*)qp;
        const u16x8 v1 = *(const u16x8*)(qp + 32);
        #pragma unroll
        for (int i = 0; i < 8; ++i) {
            aq0[i] = (__bf16)(u2f(v0[i]) * 0.125f);
            aq1[i] = (__bf16)(u2f(v1[i]) * 0.125f);
        }
    }

    float m_i = -1e30f, l_p = 0.f;     // m: row exp-base; l_p: per-lane partial
    f32x4 O[4];
    #pragma unroll
    for (int d = 0; d < 4; ++d) O[d] = (f32x4){0.f, 0.f, 0.f, 0.f};

    // per-lane K base row (frag kf adds (kf>>1)*32 + (kf&1)*4 rows)
    const int g0 = ((l15 >> 3) & 1) * 16 + ((l15 >> 2) & 1) * 8 + (l15 & 3);
    const u16* kG = qkv + ((size_t)(b * TT + g0)) * C3 + CC + h * DD + h4 * 8;
    const u16* vB = qkv + ((size_t)(b * TT + vk)) * C3 + 2 * CC + h * DD + vd;

    const int NT = qt + 1;

    // ---- prologue: K tile 0 -> regs; stage V tile 0; prefetch V tile 1 ----
    u16x8 kc[8], kn[8];
    #pragma unroll
    for (int kf = 0; kf < 4; ++kf) {
        const u16* p = kG + (size_t)((kf >> 1) * 32 + (kf & 1) * 4) * C3;
        kc[2 * kf]     = *(const u16x8*)p;
        kc[2 * kf + 1] = *(const u16x8*)(p + 32);
    }
    u16x8 vr0 = *(const u16x8*)vB;
    u16x8 vr1 = *(const u16x8*)(vB + C3);
    #pragma unroll
    for (int i = 0; i < 8; ++i)
        *(u32*)&Vt[0][vd + i][vk] = (u32)vr0[i] | ((u32)vr1[i] << 16);
    if (NT > 1) {
        const u16* vp = vB + (size_t)64 * C3;
        vr0 = *(const u16x8*)vp;
        vr1 = *(const u16x8*)(vp + C3);
    }
    __syncthreads();

    const int qg = q0 + w * 16 + l15;      // this lane's q row (global)

    for (int kt = 0; kt < NT; ++kt) {
        const int cur = kt & 1;

        // ---- S = K Q^T (K fragments in registers; scale folded into Q) ----
        f32x4 s[4];
        __builtin_amdgcn_s_setprio(1);
        #pragma unroll
        for (int kf = 0; kf < 4; ++kf) {
            f32x4 z = (f32x4){0.f, 0.f, 0.f, 0.f};
            z = mfma16(asbf(kc[2 * kf]), aq0, z);
            z = mfma16(asbf(kc[2 * kf + 1]), aq1, z);
            s[kf] = z;
        }
        __builtin_amdgcn_s_setprio(0);

        // ---- prefetch K(kt+1) -> kn; stage V(kt+1); prefetch V(kt+2) ----
        if (kt + 1 < NT) {
            const u16* kp = kG + (size_t)(kt + 1) * 64 * C3;
            #pragma unroll
            for (int kf = 0; kf < 4; ++kf) {
                const u16* p = kp + (size_t)((kf >> 1) * 32 + (kf & 1) * 4) * C3;
                kn[2 * kf]     = *(const u16x8*)p;
                kn[2 * kf + 1] = *(const u16x8*)(p + 32);
            }
            const int nb = cur ^ 1;
            #pragma unroll
            for (int i = 0; i < 8; ++i)
                *(u32*)&Vt[nb][vd + i][vk] = (u32)vr0[i] | ((u32)vr1[i] << 16);
            if (kt + 2 < NT) {
                const u16* vp = vB + (size_t)(kt + 2) * 64 * C3;
                vr0 = *(const u16x8*)vp;
                vr1 = *(const u16x8*)(vp + C3);
            }
        }

        // ---- causal mask (diagonal tile only); round-7 formula ----
        if (kt == qt) {
            #pragma unroll
            for (int kf = 0; kf < 4; ++kf) {
                const int kbase = qt * 64 + 8 * h4 + 32 * (kf >> 1) + 4 * (kf & 1);
                #pragma unroll
                for (int r2 = 0; r2 < 4; ++r2)
                    if (kbase + r2 > qg) s[kf][r2] = -1e30f;
            }
        }

        // ---- softmax, defer-max: no cross-lane ops in common path ----
        float pm = s[0][0];
        #pragma unroll
        for (int kf = 0; kf < 4; ++kf)
            #pragma unroll
            for (int r2 = 0; r2 < 4; ++r2) pm = fmaxf(pm, s[kf][r2]);

        if (!__all(pm <= m_i + 8.f)) {     // rare: raise base and rescale
            float pr = pm;
            pr = fmaxf(pr, __shfl_xor(pr, 16));
            pr = fmaxf(pr, __shfl_xor(pr, 32));
            const float mnew = fmaxf(m_i, pr);
            const float a_ = __expf(m_i - mnew);
            l_p *= a_;
            float alf[4];
            #pragma unroll
            for (int r2 = 0; r2 < 4; ++r2) alf[r2] = __shfl(a_, h4 * 4 + r2);
            #pragma unroll
            for (int d = 0; d < 4; ++d)
                #pragma unroll
                for (int r2 = 0; r2 < 4; ++r2) O[d][r2] *= alf[r2];
            m_i = mnew;
        }

        bf16x8 ap, ap2;
        float rs = 0.f;
        #pragma unroll
        for (int kf = 0; kf < 2; ++kf)
            #pragma unroll
            for (int r2 = 0; r2 < 4; ++r2) {
                const float p = __expf(s[kf][r2] - m_i);
                rs += p;
                ap[kf * 4 + r2] = (__bf16)p;
            }
        #pragma unroll
        for (int kf = 2; kf < 4; ++kf)
            #pragma unroll
            for (int r2 = 0; r2 < 4; ++r2) {
                const float p = __expf(s[kf][r2] - m_i);
                rs += p;
                ap2[(kf - 2) * 4 + r2] = (__bf16)p;
            }
        l_p += rs;                         // per-lane partial; reduced at end

        // ---- O += P V (P entirely in registers) ----
        __builtin_amdgcn_s_setprio(1);
        #pragma unroll
        for (int d = 0; d < 4; ++d) {
            O[d] = mfma16(ap,  ldsb8(&Vt[cur][d * 16 + l15][h4 * 8]), O[d]);
            O[d] = mfma16(ap2, ldsb8(&Vt[cur][d * 16 + l15][32 + h4 * 8]), O[d]);
        }
        __builtin_amdgcn_s_setprio(0);

        __syncthreads();                   // one barrier per tile (V ping-pong)

        if (kt + 1 < NT) {
            #pragma unroll
            for (int i = 0; i < 8; ++i) kc[i] = kn[i];
        }
    }

    // ---- epilogue: reduce l partials (once), normalize, store bf16 ----
    float lr = l_p;
    lr += __shfl_xor(lr, 16);
    lr += __shfl_xor(lr, 32);
    const float invl = 1.0f / lr;
    float inv[4];
    #pragma unroll
    for (int r2 = 0; r2 < 4; ++r2) inv[r2] = __shfl(invl, h4 * 4 + r2);
    u16* yp = yatt + ((size_t)(b * TT + q0 + w * 16 + h4 * 4)) * CC + h * DD + l15;
    #pragma unroll
    for (int r2 = 0; r2 < 4; ++r2)
        #pragma unroll
        for (int d = 0; d < 4; ++d)
            yp[(size_t)r2 * CC + d * 16] = f2b(O[d][r2] * inv[r2]);
}

// ---------------------------------------------------------------------------
extern "C" void kernel_launch(void* const* d_in, const int* in_sizes, int n_in,
                              void* d_out, int out_size, void* d_ws, size_t ws_size,
                              hipStream_t stream)
{
    (void)n_in; (void)out_size; (void)ws_size;

    const void* x      = d_in[0];
    const void* W_attn = d_in[1];
    const void* b_attn = d_in[2];
    const void* W_proj = d_in[3];
    const void* b_proj = d_in[4];

    // workspace layout (~30 MB)
    u16* qkv  = (u16*)d_ws;                       // [4096,2304] bf16
    u16* yatt = qkv + (size_t)MM * C3;            // [4096,768]  bf16
    u16* xb   = yatt;                             // bf16 x — lifetime disjoint
    u16* WaT  = yatt + (size_t)MM * CC;           // [2304,768]  bf16 (W_attn^T)
    u16* WpT  = WaT + (size_t)C3 * CC;            // [768,768]   bf16 (W_proj^T)
    u16* ba   = WpT + (size_t)CC * CC;            // [2304] bf16
    u16* bp   = ba + C3;                          // [768]  bf16
    int* flag = (int*)(bp + CC);                  // 1 int

    // host-side dtype inference from byte sizes; device detector as fallback
    int mode = -1;
    if (in_sizes[0] == MM * CC * 4) mode = 1;          // fp32 bytes
    else if (in_sizes[0] == MM * CC * 2) mode = 0;     // bf16 bytes
    if (mode < 0) {
        detect_kernel<<<1, 256, 0, stream>>>((const u16*)x, flag);
    }

    // fused prep: W transposes + x->bf16 (fp32 mode only) + biases
    fused_prep<<<2121, 256, 0, stream>>>(x, W_attn, b_attn, W_proj, b_proj,
                                         xb, WaT, WpT, ba, bp, flag, mode);

    // 1) qkv = x/xb @ W_attn + b_attn (bf16 out), 128x64 tiles, 1152 blocks
    gemm_mfma<4, 2><<<(MM / 128) * (C3 / 64), 256, 0, stream>>>(
        (const u16*)x, xb, WaT, ba, (void*)qkv, MM, C3, CC, flag, mode, 0);

    // 2) causal flash attention (K direct-from-global; V LDS ping-pong)
    attn_mfma<<<dim3(TT / 64 * HH * BB, 1, 1), 256, 0, stream>>>(qkv, yatt);

    // 3) out = yatt @ W_proj + b_proj (out dtype follows mode), 64x64 tiles
    gemm_mfma<2, 2><<<(MM / 64) * (CC / 64), 256, 0, stream>>>(
        yatt, yatt, WpT, bp, d_out, MM, CC, CC, flag, mode, 1);
}